// Round 1
// 5489.013 us; speedup vs baseline: 1.3769x; 1.3769x over previous
//
#include <hip/hip_runtime.h>
#include <hip/hip_bf16.h>

// BiLSTM, B=128 S=1024 D=128 H=256, transpose quirk: u_t[r][k] = x[k,t,r].
// Round 4: latency-bound on the recurrence chain (all PMC utils ~1-2%,
// 7.14us/step vs ~2.2us floor). Changes:
//  (a) h exchange read: 8x global_load_dwordx4 sc0 sc1 ALL in flight (was a
//      4-deep chain of 16 u64 atomic loads = 2-3.6us serialized).
//  (b) all-thread spin (no tid0->barrier re-broadcast); falls straight into
//      the h loads.
//  (c) wave-granular release: per-wave vmcnt(0) drain + lane0 add to its own
//      counter word; consumer polls the 16B line with two u64 loads.
//  (d) x-part GEMM (ks 0..3) before the spin; xbt prefetched into registers
//      one step ahead (issued after B2, drained by epilogue vmcnt(0)).
//  (e) h-part W fragments cached in registers (128 VGPR; 1 WG/CU is forced
//      by LDS, so VGPRs to 512/wave are free) -> h-GEMM LDS reads 48->16
//      b128/thread.
//  (f) tail __syncthreads removed (flag ordering protects Hc, B2 protects
//      Xc): 2 barriers/step.

typedef unsigned int  u32;
typedef unsigned long long u64;
typedef unsigned short u16;
typedef short short4_t __attribute__((ext_vector_type(4)));
typedef short short8_t __attribute__((ext_vector_type(8)));
typedef float float4_t __attribute__((ext_vector_type(4)));
typedef float float2_t __attribute__((ext_vector_type(2)));
typedef int   int4_t   __attribute__((ext_vector_type(4)));

#define S_LEN 1024
#define D_IN  128
#define H_DIM 256
#define B_DIM 128
#define K_DIM 384
#define LSTR  392                       // K_DIM + 8 pad (784 B rows, 16B-aligned)
#define SMEM_BYTES ((128 + 64) * LSTR * 2)   // 150528 B

// d_ws layout
#define WS_CNT_BYTES 65536              // [4 grp][1024 s][4 wave] u32 flags
#define WS_HBUF  65536                  // 256 KB h double-buffer (bf16)
#define WS_XBT   327680                 // 32 MB xbt[t][r][k] bf16
#define WS_NEED  (WS_XBT + (size_t)S_LEN * B_DIM * D_IN * 2)

__device__ __forceinline__ u16 f2bf(float f) {
    union { float f; u32 u; } v; v.f = f;
    u32 r = v.u + 0x7fffu + ((v.u >> 16) & 1u);
    return (u16)(r >> 16);
}
__device__ __forceinline__ float sig_f(float x) {
    return __builtin_amdgcn_rcpf(1.f + __expf(-x));
}
__device__ __forceinline__ float tanh_f(float x) {
    return 2.f * sig_f(2.f * x) - 1.f;
}

// ---- pre-pass: xbt[t][r][k] = bf16(x[k][t][r]) ; one WG per t ----
__global__ __launch_bounds__(256, 4)
void tx_kernel(const float* __restrict__ x, u16* __restrict__ xbt)
{
    __shared__ u16 tile[128][136];      // 272 B rows (16B-aligned)
    const int t   = blockIdx.x;
    const int tid = threadIdx.x;
    for (int c = 0; c < 16; ++c) {
        int f = tid + c * 256;          // 0..4095
        int k = f >> 5, q = f & 31;     // k row, r-chunk
        float4_t v = *(const float4_t*)(x + (size_t)k * (S_LEN * D_IN)
                                          + (size_t)t * D_IN + 4 * q);
        tile[4 * q + 0][k] = f2bf(v[0]);
        tile[4 * q + 1][k] = f2bf(v[1]);
        tile[4 * q + 2][k] = f2bf(v[2]);
        tile[4 * q + 3][k] = f2bf(v[3]);
    }
    __syncthreads();
    u16* dst = xbt + (size_t)t * (B_DIM * D_IN);
    for (int c = 0; c < 8; ++c) {
        int f = tid + c * 256;          // 0..2047
        int r = f >> 4, kc = f & 15;
        *(short8_t*)(dst + r * D_IN + kc * 8) = *(const short8_t*)(&tile[r][kc * 8]);
    }
}

__global__ __launch_bounds__(256, 1)
void bilstm_kernel(const float* __restrict__ x,
                   const float* __restrict__ Wf, const float* __restrict__ bf_,
                   const float* __restrict__ Wb, const float* __restrict__ bb_,
                   float* __restrict__ out,
                   u32* __restrict__ cnt,     // [4 grp][1024 s][4 w] (memset 0)
                   u16* __restrict__ hbuf,    // [2 dir][2 par][128 r][256 h] bf16
                   const u16* __restrict__ xbt,
                   int use_xbt)
{
    extern __shared__ char smem[];
    u16* Wl = (u16*)smem;                 // [128][LSTR]
    u16* Cc = (u16*)smem + 128 * LSTR;    // [64][LSTR]: cols 0..127 = Xc, 128..383 = Hc

    const int tid = threadIdx.x;
    const int bx  = blockIdx.x;
    const int dir = bx >> 4;              // 0 fwd, 1 bwd
    const int id  = bx & 15;
    const int bg  = id >> 3;              // r-half
    const int hs  = id & 7;               // h-slice
    const int b0  = bg * 64;
    const int h0  = hs * 32;

    const float* W    = dir ? Wb : Wf;
    const float* bias = dir ? bb_ : bf_;

    // ---- load W slice into LDS (fp32 -> bf16): row m=g*32+hl <- W[g][h0+hl][k]
    for (int it = 0; it < 48; ++it) {
        int v  = tid + it * 256;          // 0..12287 (128 rows * 96 vec4)
        int r  = v / 96;
        int kv = v - r * 96;
        int g  = r >> 5, hl = r & 31;
        const float4_t src = *(const float4_t*)(W + ((g * H_DIM + h0 + hl) * K_DIM + kv * 4));
        short4_t d;
        d[0] = (short)f2bf(src[0]); d[1] = (short)f2bf(src[1]);
        d[2] = (short)f2bf(src[2]); d[3] = (short)f2bf(src[3]);
        *(short4_t*)(Wl + r * LSTR + kv * 4) = d;
    }

    const int lane = tid & 63;
    const int wid  = tid >> 6;            // 4 waves
    const int quad = lane >> 4;
    const int l15  = lane & 15;
    const int hlt  = wid >> 1;            // m-half (16 h rows each)
    const int nh   = wid & 1;             // n-half (32 b cols each)

    float bias_r[4][4];
    #pragma unroll
    for (int g = 0; g < 4; ++g)
        #pragma unroll
        for (int i = 0; i < 4; ++i)
            bias_r[g][i] = bias[g * H_DIM + h0 + hlt * 16 + quad * 4 + i];

    float c_st[2][4];
    #pragma unroll
    for (int nt = 0; nt < 2; ++nt)
        #pragma unroll
        for (int i = 0; i < 4; ++i) c_st[nt][i] = 0.f;

    u32* grpcnt = cnt + (dir * 2 + bg) * (S_LEN * 4);

    __syncthreads();                       // W slice visible to all waves

    // ---- cache h-part W fragments (ks 4..11) in registers: 32 b128 = 128 VGPR
    short8_t areg[4][8];
    #pragma unroll
    for (int ks = 0; ks < 8; ++ks) {
        const int ko = (ks + 4) * 32 + quad * 8;
        #pragma unroll
        for (int g = 0; g < 4; ++g)
            areg[g][ks] = *(const short8_t*)(Wl + (g * 32 + hlt * 16 + l15) * LSTR + ko);
    }

    // ---- xbt prefetch (one step ahead) ----
    short8_t xv[4];
    auto XLOAD = [&](int tt) {
        const u16* xs = xbt + (size_t)tt * (B_DIM * D_IN) + b0 * D_IN;
        #pragma unroll
        for (int it = 0; it < 4; ++it) {
            int f = tid + it * 256;       // 0..1023 (64 rows * 16 chunks)
            int r = f >> 4, kc = f & 15;
            xv[it] = *(const short8_t*)(xs + r * D_IN + kc * 8);
        }
    };
    if (use_xbt) XLOAD(dir ? (S_LEN - 1) : 0);

    for (int s = 0; s < S_LEN; ++s) {
        const int t = dir ? (S_LEN - 1 - s) : s;

        // ---- stage u_t into Xc (prefetched regs -> pure ds_writes) ----
        if (use_xbt) {
            #pragma unroll
            for (int it = 0; it < 4; ++it) {
                int f = tid + it * 256;
                int r = f >> 4, kc = f & 15;
                *(short8_t*)(Cc + r * LSTR + kc * 8) = xv[it];
            }
        } else {
            const int m  = tid & 31;
            const int kb = tid >> 5;
            const float* xcol = x + (size_t)t * D_IN + b0 + 2 * m;
            for (int it = 0; it < 16; ++it) {
                int k = it * 8 + kb;
                float2_t v = *(const float2_t*)(xcol + (size_t)k * (S_LEN * D_IN));
                Cc[(2 * m) * LSTR + k]     = f2bf(v[0]);
                Cc[(2 * m + 1) * LSTR + k] = f2bf(v[1]);
            }
        }
        __syncthreads();                   // B1: Xc staged

        float4_t acc[4][2];
        #pragma unroll
        for (int g = 0; g < 4; ++g) {
            acc[g][0] = (float4_t){0.f, 0.f, 0.f, 0.f};
            acc[g][1] = (float4_t){0.f, 0.f, 0.f, 0.f};
        }

        // ---- x-part GEMM (ks 0..3) -- overlaps producers' flag propagation
        #pragma unroll
        for (int ks = 0; ks < 4; ++ks) {
            const int ko = ks * 32 + quad * 8;
            short8_t a[4], bb[2];
            #pragma unroll
            for (int g = 0; g < 4; ++g)
                a[g] = *(const short8_t*)(Wl + (g * 32 + hlt * 16 + l15) * LSTR + ko);
            #pragma unroll
            for (int nt = 0; nt < 2; ++nt)
                bb[nt] = *(const short8_t*)(Cc + (nh * 32 + nt * 16 + l15) * LSTR + ko);
            #pragma unroll
            for (int g = 0; g < 4; ++g)
                #pragma unroll
                for (int nt = 0; nt < 2; ++nt)
                    acc[g][nt] = __builtin_amdgcn_mfma_f32_16x16x32_bf16(
                        a[g], bb[nt], acc[g][nt], 0, 0, 0);
        }

        // ---- spin (all threads) + batched h load ----
        u16* cw = Cc + (tid >> 2) * LSTR + D_IN + 64 * (tid & 3);
        if (s > 0) {
            const u64* fp = (const u64*)(grpcnt + (s - 1) * 4);
            const u64 tgt = 0x0000000800000008ull;   // 4 words, each == 8 WGs
            for (;;) {
                u64 w0 = __hip_atomic_load(fp,     __ATOMIC_RELAXED,
                                           __HIP_MEMORY_SCOPE_AGENT);
                u64 w1 = __hip_atomic_load(fp + 1, __ATOMIC_RELAXED,
                                           __HIP_MEMORY_SCOPE_AGENT);
                if (w0 == tgt && w1 == tgt) break;
                __builtin_amdgcn_s_sleep(1);
            }
            const int par_r = (s - 1) & 1;
            const u16* hb = hbuf + ((size_t)((dir * 2 + par_r) * B_DIM + b0 + (tid >> 2)))
                                  * H_DIM + 64 * (tid & 3);
            int4_t hv[8];
#define HL(i, OFF) asm volatile("global_load_dwordx4 %0, %1, off offset:" OFF " sc0 sc1" \
                                : "=v"(hv[i]) : "v"(hb) : "memory")
            HL(0, "0");  HL(1, "16"); HL(2, "32"); HL(3, "48");
            HL(4, "64"); HL(5, "80"); HL(6, "96"); HL(7, "112");
#undef HL
            asm volatile("s_waitcnt vmcnt(0)" ::: "memory");
            #pragma unroll
            for (int it = 0; it < 8; ++it)
                *(int4_t*)(cw + 8 * it) = hv[it];
        } else {
            int4_t z4 = (int4_t){0, 0, 0, 0};
            #pragma unroll
            for (int it = 0; it < 8; ++it)
                *(int4_t*)(cw + 8 * it) = z4;
        }
        __syncthreads();                   // B2: Hc staged

        // ---- prefetch next-step xbt (drains under h-GEMM + epilogue) ----
        if (use_xbt && s + 1 < S_LEN)
            XLOAD(dir ? (S_LEN - 2 - s) : (s + 1));

        // ---- h-part GEMM (ks 4..11), A from registers ----
        #pragma unroll
        for (int ks = 0; ks < 8; ++ks) {
            const int ko = (ks + 4) * 32 + quad * 8;
            short8_t bb0 = *(const short8_t*)(Cc + (nh * 32 + l15) * LSTR + ko);
            short8_t bb1 = *(const short8_t*)(Cc + (nh * 32 + 16 + l15) * LSTR + ko);
            #pragma unroll
            for (int g = 0; g < 4; ++g) {
                acc[g][0] = __builtin_amdgcn_mfma_f32_16x16x32_bf16(
                    areg[g][ks], bb0, acc[g][0], 0, 0, 0);
                acc[g][1] = __builtin_amdgcn_mfma_f32_16x16x32_bf16(
                    areg[g][ks], bb1, acc[g][1], 0, 0, 0);
            }
        }

        // ---- activations + state update + outputs (fp32 epilogue) ----
        const int par_w = s & 1;
        u16* hdst = hbuf + ((dir * 2 + par_w) * B_DIM) * H_DIM;
        const int hrow = h0 + hlt * 16 + quad * 4;   // this thread's 4 h rows

        #pragma unroll
        for (int nt = 0; nt < 2; ++nt) {
            const int b = b0 + nh * 32 + nt * 16 + l15;
            float hv_[4], cv[4];
            #pragma unroll
            for (int i = 0; i < 4; ++i) {
                float zf = acc[0][nt][i] + bias_r[0][i];
                float zi = acc[1][nt][i] + bias_r[1][i];
                float zc = acc[2][nt][i] + bias_r[2][i];
                float zo = acc[3][nt][i] + bias_r[3][i];
                float fg = sig_f(zf);
                float ig = sig_f(zi);
                float og = sig_f(zo);
                float ct = tanh_f(zc);
                float c  = fg * c_st[nt][i] + ig * ct;
                c_st[nt][i] = c;
                float h  = og * tanh_f(c);
                hv_[i] = h; cv[i] = c;
            }
            // h broadcast (packed bf16 u64, agent-scope relaxed)
            u64 hp = (u64)f2bf(hv_[0]) | ((u64)f2bf(hv_[1]) << 16)
                   | ((u64)f2bf(hv_[2]) << 32) | ((u64)f2bf(hv_[3]) << 48);
            __hip_atomic_store((u64*)(hdst + b * H_DIM + hrow), hp,
                               __ATOMIC_RELAXED, __HIP_MEMORY_SCOPE_AGENT);
            // output[b][t][dir*256 + h] in fp32
            float4_t ho; ho[0]=hv_[0]; ho[1]=hv_[1]; ho[2]=hv_[2]; ho[3]=hv_[3];
            *(float4_t*)(out + ((size_t)b * (S_LEN * 2 * H_DIM)
                          + (size_t)t * (2 * H_DIM) + dir * H_DIM + hrow)) = ho;
            if (s == S_LEN - 1) {  // final states (h then c), fp32
                size_t fo = (size_t)67108864 + (size_t)dir * 32768
                          + (size_t)b * H_DIM + hrow;
                *(float4_t*)(out + fo) = ho;
                float4_t co; co[0]=cv[0]; co[1]=cv[1]; co[2]=cv[2]; co[3]=cv[3];
                *(float4_t*)(out + fo + 65536) = co;
            }
        }

        // ---- wave-granular release: drain own stores, flag own word ----
        asm volatile("s_waitcnt vmcnt(0)" ::: "memory");
        if (lane == 0)
            __hip_atomic_fetch_add(grpcnt + s * 4 + wid, 1u,
                                   __ATOMIC_RELAXED, __HIP_MEMORY_SCOPE_AGENT);
        // no tail barrier: B2 orders Xc overwrite (all waves passed x-GEMM);
        // the step-s flag orders Hc overwrite (spin(s+1) needs every wave's
        // flag(s), which follows its h-GEMM reads).
    }
}

extern "C" void kernel_launch(void* const* d_in, const int* in_sizes, int n_in,
                              void* d_out, int out_size, void* d_ws, size_t ws_size,
                              hipStream_t stream) {
    (void)in_sizes; (void)n_in; (void)out_size;
    hipFuncSetAttribute((const void*)bilstm_kernel,
                        hipFuncAttributeMaxDynamicSharedMemorySize, SMEM_BYTES);
    u32* cnt  = (u32*)d_ws;
    u16* hbuf = (u16*)((char*)d_ws + WS_HBUF);
    u16* xbt  = (u16*)((char*)d_ws + WS_XBT);
    const int use_xbt = (ws_size >= WS_NEED) ? 1 : 0;
    hipMemsetAsync(d_ws, 0, WS_CNT_BYTES, stream);  // flags start at 0
    if (use_xbt)
        tx_kernel<<<dim3(S_LEN), dim3(256), 0, stream>>>((const float*)d_in[0], xbt);
    bilstm_kernel<<<dim3(32), dim3(256), SMEM_BYTES, stream>>>(
        (const float*)d_in[0], (const float*)d_in[1], (const float*)d_in[2],
        (const float*)d_in[3], (const float*)d_in[4],
        (float*)d_out, cnt, hbuf, xbt, use_xbt);
}